// Round 1
// baseline (111.580 us; speedup 1.0000x reference)
//
#include <hip/hip_runtime.h>
#include <math.h>

#define KPTS 133
#define WAVES_PER_BLOCK 4

__device__ __forceinline__ float det3(float a0, float a1, float a2,
                                      float b0, float b1, float b2,
                                      float c0, float c1, float c2) {
    return a0 * (b1 * c2 - b2 * c1)
         - a1 * (b0 * c2 - b2 * c0)
         + a2 * (b0 * c1 - b1 * c0);
}

// One wave (64 lanes) per sample. Each lane holds up to 3 points of target and
// output in registers; single pass: raw moments -> butterfly reduce -> every
// lane redundantly solves the 4x4 quaternion eigenproblem (uniform branches)
// -> residual norms from register-held points -> wave reduce -> block sum.
__global__ __launch_bounds__(256) void pa_mpjpe_kernel(
    const float* __restrict__ outp,   // (N,K,3) output
    const float* __restrict__ tgtp,   // (N,K,3) target
    float* __restrict__ block_sums,
    int nsamp)
{
    const int lane = threadIdx.x & 63;
    const int wid  = threadIdx.x >> 6;
    const int s    = blockIdx.x * WAVES_PER_BLOCK + wid;

    __shared__ float sh[WAVES_PER_BLOCK];

    float wave_sum = 0.0f;
    if (s < nsamp) {
        const float* tb = tgtp + (size_t)s * (KPTS * 3);
        const float* ob = outp + (size_t)s * (KPTS * 3);

        float tp[3][3], op[3][3];
        // red layout: [0..2]=sum_t, [3..5]=sum_o, [6..14]=C[a*3+b]=sum t_a*o_b, [15]=sum t.t
        float red[16];
        #pragma unroll
        for (int i = 0; i < 16; ++i) red[i] = 0.0f;

        #pragma unroll
        for (int j = 0; j < 3; ++j) {
            const int k = lane + 64 * j;
            const bool valid = (k < KPTS);
            float t0 = 0.f, t1 = 0.f, t2 = 0.f, o0 = 0.f, o1 = 0.f, o2 = 0.f;
            if (valid) {
                t0 = tb[3 * k + 0]; t1 = tb[3 * k + 1]; t2 = tb[3 * k + 2];
                o0 = ob[3 * k + 0]; o1 = ob[3 * k + 1]; o2 = ob[3 * k + 2];
            }
            tp[j][0] = t0; tp[j][1] = t1; tp[j][2] = t2;
            op[j][0] = o0; op[j][1] = o1; op[j][2] = o2;
            red[0]  += t0;      red[1]  += t1;      red[2]  += t2;
            red[3]  += o0;      red[4]  += o1;      red[5]  += o2;
            red[6]  += t0 * o0; red[7]  += t0 * o1; red[8]  += t0 * o2;
            red[9]  += t1 * o0; red[10] += t1 * o1; red[11] += t1 * o2;
            red[12] += t2 * o0; red[13] += t2 * o1; red[14] += t2 * o2;
            red[15] += t0 * t0 + t1 * t1 + t2 * t2;
        }

        // 64-lane butterfly reduce of all 16 accumulators (result on all lanes)
        #pragma unroll
        for (int off = 32; off >= 1; off >>= 1) {
            #pragma unroll
            for (int i = 0; i < 16; ++i)
                red[i] += __shfl_xor(red[i], off, 64);
        }

        const float invK = 1.0f / (float)KPTS;
        const float mu1x = red[0] * invK, mu1y = red[1] * invK, mu1z = red[2] * invK;
        const float mu2x = red[3] * invK, mu2y = red[4] * invK, mu2z = red[5] * invK;

        // centered cross-covariance K = X1^T X2  (K_ab = C_ab - KPTS*mu1_a*mu2_b)
        const float Sxx = red[6]  - (float)KPTS * mu1x * mu2x;
        const float Sxy = red[7]  - (float)KPTS * mu1x * mu2y;
        const float Sxz = red[8]  - (float)KPTS * mu1x * mu2z;
        const float Syx = red[9]  - (float)KPTS * mu1y * mu2x;
        const float Syy = red[10] - (float)KPTS * mu1y * mu2y;
        const float Syz = red[11] - (float)KPTS * mu1y * mu2z;
        const float Szx = red[12] - (float)KPTS * mu1z * mu2x;
        const float Szy = red[13] - (float)KPTS * mu1z * mu2y;
        const float Szz = red[14] - (float)KPTS * mu1z * mu2z;
        const float var1 = red[15] - (float)KPTS * (mu1x * mu1x + mu1y * mu1y + mu1z * mu1z);

        // Horn's 4x4 symmetric quaternion matrix
        const float N00 = Sxx + Syy + Szz;
        const float N01 = Syz - Szy, N02 = Szx - Sxz, N03 = Sxy - Syx;
        const float N11 = Sxx - Syy - Szz, N12 = Sxy + Syx, N13 = Szx + Sxz;
        const float N22 = -Sxx + Syy - Szz, N23 = Syz + Szy;
        const float N33 = -Sxx - Syy + Szz;

        // characteristic polynomial: l^4 + c2 l^2 + c1 l + c0
        const float trKtK = Sxx * Sxx + Sxy * Sxy + Sxz * Sxz
                          + Syx * Syx + Syy * Syy + Syz * Syz
                          + Szx * Szx + Szy * Szy + Szz * Szz;
        const float c2 = -2.0f * trKtK;
        const float detK = det3(Sxx, Sxy, Sxz, Syx, Syy, Syz, Szx, Szy, Szz);
        const float c1 = -8.0f * detK;
        const float c0 =
              N00 * det3(N11, N12, N13, N12, N22, N23, N13, N23, N33)
            - N01 * det3(N01, N12, N13, N02, N22, N23, N03, N23, N33)
            + N02 * det3(N01, N11, N13, N02, N12, N23, N03, N13, N33)
            - N03 * det3(N01, N11, N12, N02, N12, N22, N03, N13, N23);

        // Newton from guaranteed upper bound lam0 = sqrt(3 * tr(K^T K)) >= s1+s2+s3 >= lam_max
        float lam = sqrtf(fmaxf(3.0f * trKtK, 0.0f));
        #pragma unroll
        for (int it = 0; it < 14; ++it) {
            const float l2 = lam * lam;
            const float P  = (l2 + c2) * l2 + c1 * lam + c0;
            const float Pp = (4.0f * l2 + 2.0f * c2) * lam + c1;
            lam -= P / Pp;
        }

        // eigenvector of (N - lam I) via adjugate rows 0 and 1 (pick larger norm)
        const float M00 = N00 - lam, M11 = N11 - lam, M22 = N22 - lam, M33 = N33 - lam;
        const float a0 =  det3(M11, N12, N13, N12, M22, N23, N13, N23, M33);
        const float a1 = -det3(N01, N12, N13, N02, M22, N23, N03, N23, M33);
        const float a2 =  det3(N01, M11, N13, N02, N12, N23, N03, N13, M33);
        const float a3 = -det3(N01, M11, N12, N02, N12, M22, N03, N13, N23);
        const float b0 = -det3(N01, N02, N03, N12, M22, N23, N13, N23, M33);
        const float b1 =  det3(M00, N02, N03, N02, M22, N23, N03, N23, M33);
        const float b2 = -det3(M00, N01, N03, N02, N12, N23, N03, N13, M33);
        const float b3 =  det3(M00, N01, N02, N02, N12, M22, N03, N13, N23);
        const float na = a0 * a0 + a1 * a1 + a2 * a2 + a3 * a3;
        const float nb = b0 * b0 + b1 * b1 + b2 * b2 + b3 * b3;
        float qw, qx, qy, qz;
        if (na >= nb) { qw = a0; qx = a1; qy = a2; qz = a3; }
        else          { qw = b0; qx = b1; qy = b2; qz = b3; }
        const float qn = rsqrtf(fmaxf(qw * qw + qx * qx + qy * qy + qz * qz, 1e-30f));
        qw *= qn; qx *= qn; qy *= qn; qz *= qn;

        // R from quaternion (rotates target toward output; det(R)=+1)
        const float R00 = 1.0f - 2.0f * (qy * qy + qz * qz);
        const float R01 = 2.0f * (qx * qy - qw * qz);
        const float R02 = 2.0f * (qx * qz + qw * qy);
        const float R10 = 2.0f * (qx * qy + qw * qz);
        const float R11 = 1.0f - 2.0f * (qx * qx + qz * qz);
        const float R12 = 2.0f * (qy * qz - qw * qx);
        const float R20 = 2.0f * (qx * qz - qw * qy);
        const float R21 = 2.0f * (qy * qz + qw * qx);
        const float R22 = 1.0f - 2.0f * (qx * qx + qy * qy);

        // scale = trace(R @ K) / var1
        const float trRK = R00 * Sxx + R01 * Syx + R02 * Szx
                         + R10 * Sxy + R11 * Syy + R12 * Szy
                         + R20 * Sxz + R21 * Syz + R22 * Szz;
        const float scale = trRK / var1;

        // t = mu2 - scale * R mu1
        const float tx = mu2x - scale * (R00 * mu1x + R01 * mu1y + R02 * mu1z);
        const float ty = mu2y - scale * (R10 * mu1x + R11 * mu1y + R12 * mu1z);
        const float tz = mu2z - scale * (R20 * mu1x + R21 * mu1y + R22 * mu1z);

        // residual norms from register-held points
        float rsum = 0.0f;
        #pragma unroll
        for (int j = 0; j < 3; ++j) {
            const int k = lane + 64 * j;
            if (k < KPTS) {
                const float ax = scale * (R00 * tp[j][0] + R01 * tp[j][1] + R02 * tp[j][2]) + tx;
                const float ay = scale * (R10 * tp[j][0] + R11 * tp[j][1] + R12 * tp[j][2]) + ty;
                const float az = scale * (R20 * tp[j][0] + R21 * tp[j][1] + R22 * tp[j][2]) + tz;
                const float dx = op[j][0] - ax;
                const float dy = op[j][1] - ay;
                const float dz = op[j][2] - az;
                rsum += sqrtf(dx * dx + dy * dy + dz * dz);
            }
        }
        #pragma unroll
        for (int off = 32; off >= 1; off >>= 1)
            rsum += __shfl_xor(rsum, off, 64);
        wave_sum = rsum;
    }

    if (lane == 0) sh[wid] = wave_sum;
    __syncthreads();
    if (threadIdx.x == 0) {
        float b = 0.0f;
        #pragma unroll
        for (int i = 0; i < WAVES_PER_BLOCK; ++i) b += sh[i];
        block_sums[blockIdx.x] = b;
    }
}

// Deterministic final reduction: one block, fixed summation order.
__global__ __launch_bounds__(256) void pa_reduce_kernel(
    const float* __restrict__ block_sums, int n,
    float* __restrict__ out, float inv_total)
{
    __shared__ float sh[4];
    float v = 0.0f;
    for (int i = threadIdx.x; i < n; i += 256) v += block_sums[i];
    #pragma unroll
    for (int off = 32; off >= 1; off >>= 1) v += __shfl_xor(v, off, 64);
    const int lane = threadIdx.x & 63;
    const int wid  = threadIdx.x >> 6;
    if (lane == 0) sh[wid] = v;
    __syncthreads();
    if (threadIdx.x == 0) out[0] = (sh[0] + sh[1] + sh[2] + sh[3]) * inv_total;
}

extern "C" void kernel_launch(void* const* d_in, const int* in_sizes, int n_in,
                              void* d_out, int out_size, void* d_ws, size_t ws_size,
                              hipStream_t stream) {
    const float* outp = (const float*)d_in[0];   // "output"
    const float* tgtp = (const float*)d_in[1];   // "target"
    const int nsamp   = in_sizes[0] / (KPTS * 3);
    const int nblocks = (nsamp + WAVES_PER_BLOCK - 1) / WAVES_PER_BLOCK;

    float* bsums = (float*)d_ws;

    pa_mpjpe_kernel<<<nblocks, 256, 0, stream>>>(outp, tgtp, bsums, nsamp);
    pa_reduce_kernel<<<1, 256, 0, stream>>>(
        bsums, nblocks, (float*)d_out,
        1.0f / ((float)nsamp * (float)KPTS));
}

// Round 2
// 71.113 us; speedup vs baseline: 1.5691x; 1.5691x over previous
//
#include <hip/hip_runtime.h>
#include <math.h>

#define KPTS 133
#define WPB 8   // waves (= samples) per block, block = 512 threads

__device__ __forceinline__ float det3(float a0, float a1, float a2,
                                      float b0, float b1, float b2,
                                      float c0, float c1, float c2) {
    return a0 * (b1 * c2 - b2 * c1)
         - a1 * (b0 * c2 - b2 * c0)
         + a2 * (b0 * c1 - b1 * c0);
}

// Phase 1: one wave per sample computes 16 raw moments, value-splitting
//          butterfly reduce (17 shuffles instead of 96), lane i<16 holds
//          moment i -> LDS.
// Phase 2: lanes 0..7 of wave 0 each solve ONE sample's 4x4 quaternion
//          eigenproblem (amortizes the ~550-inst scalar solve 8x/sample
//          instead of running it redundantly on 64 lanes of every wave).
//          Writes {scale*R (9), t (3)} to LDS.
// Phase 3: each wave re-reads its points (L2-hot) and accumulates residual
//          norms; wave reduce; block sum -> deterministic final reduce.
__global__ __launch_bounds__(512, 8) void pa_mpjpe_kernel(
    const float* __restrict__ outp,   // (N,K,3) output
    const float* __restrict__ tgtp,   // (N,K,3) target
    float* __restrict__ block_sums,
    int nsamp)
{
    const int lane = threadIdx.x & 63;
    const int wid  = threadIdx.x >> 6;
    const int base = blockIdx.x * WPB;
    const int s    = base + wid;
    const bool valid = (s < nsamp);

    __shared__ float mom[WPB][17];  // 16 raw moments per sample (stride 17: conflict-free)
    __shared__ float prm[WPB][16];  // sR(9), t(3); 64B rows for float4 broadcast reads
    __shared__ float shs[WPB];

    const float* tb = tgtp + (size_t)(valid ? s : 0) * (KPTS * 3);
    const float* ob = outp + (size_t)(valid ? s : 0) * (KPTS * 3);

    // ---- phase 1: raw moments ----
    // red: [0..2]=sum_t, [3..5]=sum_o, [6..14]=sum t_a*o_b (row-major), [15]=sum t.t
    float red[16];
    #pragma unroll
    for (int i = 0; i < 16; ++i) red[i] = 0.0f;

    if (valid) {
        #pragma unroll
        for (int j = 0; j < 3; ++j) {
            const int k = lane + 64 * j;
            if (k < KPTS) {
                const float t0 = tb[3 * k + 0], t1 = tb[3 * k + 1], t2 = tb[3 * k + 2];
                const float o0 = ob[3 * k + 0], o1 = ob[3 * k + 1], o2 = ob[3 * k + 2];
                red[0]  += t0;      red[1]  += t1;      red[2]  += t2;
                red[3]  += o0;      red[4]  += o1;      red[5]  += o2;
                red[6]  += t0 * o0; red[7]  += t0 * o1; red[8]  += t0 * o2;
                red[9]  += t1 * o0; red[10] += t1 * o1; red[11] += t1 * o2;
                red[12] += t2 * o0; red[13] += t2 * o1; red[14] += t2 * o2;
                red[15] += t0 * t0 + t1 * t1 + t2 * t2;
            }
        }
    }

    // value-splitting butterfly: after 4 halving stages + 2 plain stages,
    // lane l holds the full 64-lane sum of red[l & 15].
    float v8[8];
    {
        const bool b = (lane & 1);
        #pragma unroll
        for (int m = 0; m < 8; ++m) {
            const float snd = b ? red[2 * m] : red[2 * m + 1];
            const float rcv = __shfl_xor(snd, 1, 64);
            v8[m] = (b ? red[2 * m + 1] : red[2 * m]) + rcv;
        }
    }
    float v4[4];
    {
        const bool b = ((lane >> 1) & 1);
        #pragma unroll
        for (int m = 0; m < 4; ++m) {
            const float snd = b ? v8[2 * m] : v8[2 * m + 1];
            const float rcv = __shfl_xor(snd, 2, 64);
            v4[m] = (b ? v8[2 * m + 1] : v8[2 * m]) + rcv;
        }
    }
    float v2[2];
    {
        const bool b = ((lane >> 2) & 1);
        #pragma unroll
        for (int m = 0; m < 2; ++m) {
            const float snd = b ? v4[2 * m] : v4[2 * m + 1];
            const float rcv = __shfl_xor(snd, 4, 64);
            v2[m] = (b ? v4[2 * m + 1] : v4[2 * m]) + rcv;
        }
    }
    float v1;
    {
        const bool b = ((lane >> 3) & 1);
        const float snd = b ? v2[0] : v2[1];
        const float rcv = __shfl_xor(snd, 8, 64);
        v1 = (b ? v2[1] : v2[0]) + rcv;
    }
    v1 += __shfl_xor(v1, 16, 64);
    v1 += __shfl_xor(v1, 32, 64);

    if (lane < 16) mom[wid][lane] = v1;
    __syncthreads();

    // ---- phase 2: per-lane eigen solve (wave 0, lanes 0..WPB-1) ----
    if (wid == 0 && lane < WPB && (base + lane) < nsamp) {
        float m_[16];
        #pragma unroll
        for (int j = 0; j < 16; ++j) m_[j] = mom[lane][j];

        const float invK = 1.0f / (float)KPTS;
        const float mu1x = m_[0] * invK, mu1y = m_[1] * invK, mu1z = m_[2] * invK;
        const float mu2x = m_[3] * invK, mu2y = m_[4] * invK, mu2z = m_[5] * invK;

        // centered cross-covariance S_ab = C_ab - sum_t_a*sum_o_b/K
        const float Sxx = m_[6]  - m_[0] * m_[3] * invK;
        const float Sxy = m_[7]  - m_[0] * m_[4] * invK;
        const float Sxz = m_[8]  - m_[0] * m_[5] * invK;
        const float Syx = m_[9]  - m_[1] * m_[3] * invK;
        const float Syy = m_[10] - m_[1] * m_[4] * invK;
        const float Syz = m_[11] - m_[1] * m_[5] * invK;
        const float Szx = m_[12] - m_[2] * m_[3] * invK;
        const float Szy = m_[13] - m_[2] * m_[4] * invK;
        const float Szz = m_[14] - m_[2] * m_[5] * invK;
        const float var1 = m_[15] - (m_[0] * m_[0] + m_[1] * m_[1] + m_[2] * m_[2]) * invK;

        // Horn's 4x4 symmetric quaternion matrix
        const float N00 = Sxx + Syy + Szz;
        const float N01 = Syz - Szy, N02 = Szx - Sxz, N03 = Sxy - Syx;
        const float N11 = Sxx - Syy - Szz, N12 = Sxy + Syx, N13 = Szx + Sxz;
        const float N22 = -Sxx + Syy - Szz, N23 = Syz + Szy;
        const float N33 = -Sxx - Syy + Szz;

        // characteristic polynomial l^4 + c2 l^2 + c1 l + c0
        const float trKtK = Sxx * Sxx + Sxy * Sxy + Sxz * Sxz
                          + Syx * Syx + Syy * Syy + Syz * Syz
                          + Szx * Szx + Szy * Szy + Szz * Szz;
        const float c2 = -2.0f * trKtK;
        const float detK = det3(Sxx, Sxy, Sxz, Syx, Syy, Syz, Szx, Szy, Szz);
        const float c1 = -8.0f * detK;
        const float c0 =
              N00 * det3(N11, N12, N13, N12, N22, N23, N13, N23, N33)
            - N01 * det3(N01, N12, N13, N02, N22, N23, N03, N23, N33)
            + N02 * det3(N01, N11, N13, N02, N12, N23, N03, N13, N33)
            - N03 * det3(N01, N11, N12, N02, N12, N22, N03, N13, N23);

        // Newton from guaranteed upper bound sqrt(3*trKtK) >= s1+s2+s3 >= lam_max
        float lam = sqrtf(fmaxf(3.0f * trKtK, 0.0f));
        #pragma unroll
        for (int it = 0; it < 14; ++it) {
            const float l2 = lam * lam;
            const float P  = (l2 + c2) * l2 + c1 * lam + c0;
            const float Pp = (4.0f * l2 + 2.0f * c2) * lam + c1;
            lam -= P / Pp;
        }

        // eigenvector of (N - lam I) via adjugate rows 0 and 1 (pick larger)
        const float M00 = N00 - lam, M11 = N11 - lam, M22 = N22 - lam, M33 = N33 - lam;
        const float a0 =  det3(M11, N12, N13, N12, M22, N23, N13, N23, M33);
        const float a1 = -det3(N01, N12, N13, N02, M22, N23, N03, N23, M33);
        const float a2 =  det3(N01, M11, N13, N02, N12, N23, N03, N13, M33);
        const float a3 = -det3(N01, M11, N12, N02, N12, M22, N03, N13, N23);
        const float b0 = -det3(N01, N02, N03, N12, M22, N23, N13, N23, M33);
        const float b1 =  det3(M00, N02, N03, N02, M22, N23, N03, N23, M33);
        const float b2 = -det3(M00, N01, N03, N02, N12, N23, N03, N13, M33);
        const float b3 =  det3(M00, N01, N02, N02, N12, M22, N03, N13, N23);
        const float na = a0 * a0 + a1 * a1 + a2 * a2 + a3 * a3;
        const float nb = b0 * b0 + b1 * b1 + b2 * b2 + b3 * b3;
        float qw, qx, qy, qz;
        if (na >= nb) { qw = a0; qx = a1; qy = a2; qz = a3; }
        else          { qw = b0; qx = b1; qy = b2; qz = b3; }
        const float qn = rsqrtf(fmaxf(qw * qw + qx * qx + qy * qy + qz * qz, 1e-30f));
        qw *= qn; qx *= qn; qy *= qn; qz *= qn;

        const float R00 = 1.0f - 2.0f * (qy * qy + qz * qz);
        const float R01 = 2.0f * (qx * qy - qw * qz);
        const float R02 = 2.0f * (qx * qz + qw * qy);
        const float R10 = 2.0f * (qx * qy + qw * qz);
        const float R11 = 1.0f - 2.0f * (qx * qx + qz * qz);
        const float R12 = 2.0f * (qy * qz - qw * qx);
        const float R20 = 2.0f * (qx * qz - qw * qy);
        const float R21 = 2.0f * (qy * qz + qw * qx);
        const float R22 = 1.0f - 2.0f * (qx * qx + qy * qy);

        const float trRK = R00 * Sxx + R01 * Syx + R02 * Szx
                         + R10 * Sxy + R11 * Syy + R12 * Szy
                         + R20 * Sxz + R21 * Syz + R22 * Szz;
        const float scale = trRK / var1;

        const float tx = mu2x - scale * (R00 * mu1x + R01 * mu1y + R02 * mu1z);
        const float ty = mu2y - scale * (R10 * mu1x + R11 * mu1y + R12 * mu1z);
        const float tz = mu2z - scale * (R20 * mu1x + R21 * mu1y + R22 * mu1z);

        // store scale-folded rotation + translation
        prm[lane][0] = scale * R00; prm[lane][1] = scale * R01; prm[lane][2] = scale * R02;
        prm[lane][3] = scale * R10; prm[lane][4] = scale * R11; prm[lane][5] = scale * R12;
        prm[lane][6] = scale * R20; prm[lane][7] = scale * R21; prm[lane][8] = scale * R22;
        prm[lane][9] = tx; prm[lane][10] = ty; prm[lane][11] = tz;
    }
    __syncthreads();

    // ---- phase 3: residual norms (re-read points, L2-hot) ----
    float rsum = 0.0f;
    if (valid) {
        const float4* p4 = (const float4*)(&prm[wid][0]);
        const float4 pa = p4[0], pb = p4[1], pc = p4[2];
        const float sR00 = pa.x, sR01 = pa.y, sR02 = pa.z, sR10 = pa.w;
        const float sR11 = pb.x, sR12 = pb.y, sR20 = pb.z, sR21 = pb.w;
        const float sR22 = pc.x, tx = pc.y, ty = pc.z, tz = pc.w;

        #pragma unroll
        for (int j = 0; j < 3; ++j) {
            const int k = lane + 64 * j;
            if (k < KPTS) {
                const float t0 = tb[3 * k + 0], t1 = tb[3 * k + 1], t2 = tb[3 * k + 2];
                const float o0 = ob[3 * k + 0], o1 = ob[3 * k + 1], o2 = ob[3 * k + 2];
                const float ax = sR00 * t0 + sR01 * t1 + sR02 * t2 + tx;
                const float ay = sR10 * t0 + sR11 * t1 + sR12 * t2 + ty;
                const float az = sR20 * t0 + sR21 * t1 + sR22 * t2 + tz;
                const float dx = o0 - ax;
                const float dy = o1 - ay;
                const float dz = o2 - az;
                rsum += sqrtf(dx * dx + dy * dy + dz * dz);
            }
        }
    }
    #pragma unroll
    for (int off = 32; off >= 1; off >>= 1)
        rsum += __shfl_xor(rsum, off, 64);

    if (lane == 0) shs[wid] = rsum;
    __syncthreads();
    if (threadIdx.x == 0) {
        float b = 0.0f;
        #pragma unroll
        for (int i = 0; i < WPB; ++i) b += shs[i];
        block_sums[blockIdx.x] = b;
    }
}

// Deterministic final reduction: one block, fixed summation order.
__global__ __launch_bounds__(256) void pa_reduce_kernel(
    const float* __restrict__ block_sums, int n,
    float* __restrict__ out, float inv_total)
{
    __shared__ float sh[4];
    float v = 0.0f;
    for (int i = threadIdx.x; i < n; i += 256) v += block_sums[i];
    #pragma unroll
    for (int off = 32; off >= 1; off >>= 1) v += __shfl_xor(v, off, 64);
    const int lane = threadIdx.x & 63;
    const int wid  = threadIdx.x >> 6;
    if (lane == 0) sh[wid] = v;
    __syncthreads();
    if (threadIdx.x == 0) out[0] = (sh[0] + sh[1] + sh[2] + sh[3]) * inv_total;
}

extern "C" void kernel_launch(void* const* d_in, const int* in_sizes, int n_in,
                              void* d_out, int out_size, void* d_ws, size_t ws_size,
                              hipStream_t stream) {
    const float* outp = (const float*)d_in[0];   // "output"
    const float* tgtp = (const float*)d_in[1];   // "target"
    const int nsamp   = in_sizes[0] / (KPTS * 3);
    const int nblocks = (nsamp + WPB - 1) / WPB;

    float* bsums = (float*)d_ws;

    pa_mpjpe_kernel<<<nblocks, 512, 0, stream>>>(outp, tgtp, bsums, nsamp);
    pa_reduce_kernel<<<1, 256, 0, stream>>>(
        bsums, nblocks, (float*)d_out,
        1.0f / ((float)nsamp * (float)KPTS));
}

// Round 3
// 67.858 us; speedup vs baseline: 1.6443x; 1.0480x over previous
//
#include <hip/hip_runtime.h>
#include <math.h>

#define KPTS 133
#define WPB 8   // waves (= samples) per block, block = 512 threads

__device__ __forceinline__ float det3(float a0, float a1, float a2,
                                      float b0, float b1, float b2,
                                      float c0, float c1, float c2) {
    return a0 * (b1 * c2 - b2 * c1)
         - a1 * (b0 * c2 - b2 * c0)
         + a2 * (b0 * c1 - b1 * c0);
}

// Single-pass version: each lane holds its 2-3 points of target AND output in
// registers (18 VGPRs) across all phases -> phase 3 needs NO global re-read
// (round-2 re-read cost: +35 MB HBM + 209 MB L2/L3 traffic).
// Phase 1: raw moments + value-splitting butterfly (17 shuffles), lane i<16
//          holds moment i -> LDS.
// Phase 2: lanes 0..7 of wave 0 solve one sample each (8x amortized Horn
//          quaternion eigenproblem), {scale*R, t} -> LDS.
// Phase 3: residual norms from register-held points; wave reduce; block sum.
__global__ __launch_bounds__(512, 8) void pa_mpjpe_kernel(
    const float* __restrict__ outp,   // (N,K,3) output
    const float* __restrict__ tgtp,   // (N,K,3) target
    float* __restrict__ block_sums,
    int nsamp)
{
    const int lane = threadIdx.x & 63;
    const int wid  = threadIdx.x >> 6;
    const int base = blockIdx.x * WPB;
    const int s    = base + wid;
    const bool valid = (s < nsamp);

    __shared__ float mom[WPB][17];  // 16 raw moments per sample (stride 17: conflict-free)
    __shared__ float prm[WPB][16];  // sR(9), t(3); 64B rows, broadcast float4 reads
    __shared__ float shs[WPB];

    const float* tb = tgtp + (size_t)(valid ? s : 0) * (KPTS * 3);
    const float* ob = outp + (size_t)(valid ? s : 0) * (KPTS * 3);

    // ---- phase 1: load points into registers, accumulate raw moments ----
    // red: [0..2]=sum_t, [3..5]=sum_o, [6..14]=sum t_a*o_b (row-major), [15]=sum t.t
    float tp[3][3], op[3][3];
    float red[16];
    #pragma unroll
    for (int i = 0; i < 16; ++i) red[i] = 0.0f;

    #pragma unroll
    for (int j = 0; j < 3; ++j) {
        const int k = lane + 64 * j;
        float t0 = 0.f, t1 = 0.f, t2 = 0.f, o0 = 0.f, o1 = 0.f, o2 = 0.f;
        if (valid && k < KPTS) {
            t0 = tb[3 * k + 0]; t1 = tb[3 * k + 1]; t2 = tb[3 * k + 2];
            o0 = ob[3 * k + 0]; o1 = ob[3 * k + 1]; o2 = ob[3 * k + 2];
        }
        tp[j][0] = t0; tp[j][1] = t1; tp[j][2] = t2;
        op[j][0] = o0; op[j][1] = o1; op[j][2] = o2;
        red[0]  += t0;      red[1]  += t1;      red[2]  += t2;
        red[3]  += o0;      red[4]  += o1;      red[5]  += o2;
        red[6]  += t0 * o0; red[7]  += t0 * o1; red[8]  += t0 * o2;
        red[9]  += t1 * o0; red[10] += t1 * o1; red[11] += t1 * o2;
        red[12] += t2 * o0; red[13] += t2 * o1; red[14] += t2 * o2;
        red[15] += t0 * t0 + t1 * t1 + t2 * t2;
    }

    // value-splitting butterfly: after 4 halving stages + 2 plain stages,
    // lane l holds the full 64-lane sum of red[l & 15].
    float v8[8];
    {
        const bool b = (lane & 1);
        #pragma unroll
        for (int m = 0; m < 8; ++m) {
            const float snd = b ? red[2 * m] : red[2 * m + 1];
            const float rcv = __shfl_xor(snd, 1, 64);
            v8[m] = (b ? red[2 * m + 1] : red[2 * m]) + rcv;
        }
    }
    float v4[4];
    {
        const bool b = ((lane >> 1) & 1);
        #pragma unroll
        for (int m = 0; m < 4; ++m) {
            const float snd = b ? v8[2 * m] : v8[2 * m + 1];
            const float rcv = __shfl_xor(snd, 2, 64);
            v4[m] = (b ? v8[2 * m + 1] : v8[2 * m]) + rcv;
        }
    }
    float v2[2];
    {
        const bool b = ((lane >> 2) & 1);
        #pragma unroll
        for (int m = 0; m < 2; ++m) {
            const float snd = b ? v4[2 * m] : v4[2 * m + 1];
            const float rcv = __shfl_xor(snd, 4, 64);
            v2[m] = (b ? v4[2 * m + 1] : v4[2 * m]) + rcv;
        }
    }
    float v1;
    {
        const bool b = ((lane >> 3) & 1);
        const float snd = b ? v2[0] : v2[1];
        const float rcv = __shfl_xor(snd, 8, 64);
        v1 = (b ? v2[1] : v2[0]) + rcv;
    }
    v1 += __shfl_xor(v1, 16, 64);
    v1 += __shfl_xor(v1, 32, 64);

    if (lane < 16) mom[wid][lane] = v1;
    __syncthreads();

    // ---- phase 2: per-lane eigen solve (wave 0, lanes 0..WPB-1) ----
    if (wid == 0 && lane < WPB && (base + lane) < nsamp) {
        float m_[16];
        #pragma unroll
        for (int j = 0; j < 16; ++j) m_[j] = mom[lane][j];

        const float invK = 1.0f / (float)KPTS;
        const float mu1x = m_[0] * invK, mu1y = m_[1] * invK, mu1z = m_[2] * invK;
        const float mu2x = m_[3] * invK, mu2y = m_[4] * invK, mu2z = m_[5] * invK;

        // centered cross-covariance S_ab = C_ab - sum_t_a*sum_o_b/K
        const float Sxx = m_[6]  - m_[0] * m_[3] * invK;
        const float Sxy = m_[7]  - m_[0] * m_[4] * invK;
        const float Sxz = m_[8]  - m_[0] * m_[5] * invK;
        const float Syx = m_[9]  - m_[1] * m_[3] * invK;
        const float Syy = m_[10] - m_[1] * m_[4] * invK;
        const float Syz = m_[11] - m_[1] * m_[5] * invK;
        const float Szx = m_[12] - m_[2] * m_[3] * invK;
        const float Szy = m_[13] - m_[2] * m_[4] * invK;
        const float Szz = m_[14] - m_[2] * m_[5] * invK;
        const float var1 = m_[15] - (m_[0] * m_[0] + m_[1] * m_[1] + m_[2] * m_[2]) * invK;

        // Horn's 4x4 symmetric quaternion matrix
        const float N00 = Sxx + Syy + Szz;
        const float N01 = Syz - Szy, N02 = Szx - Sxz, N03 = Sxy - Syx;
        const float N11 = Sxx - Syy - Szz, N12 = Sxy + Syx, N13 = Szx + Sxz;
        const float N22 = -Sxx + Syy - Szz, N23 = Syz + Szy;
        const float N33 = -Sxx - Syy + Szz;

        // characteristic polynomial l^4 + c2 l^2 + c1 l + c0
        const float trKtK = Sxx * Sxx + Sxy * Sxy + Sxz * Sxz
                          + Syx * Syx + Syy * Syy + Syz * Syz
                          + Szx * Szx + Szy * Szy + Szz * Szz;
        const float c2 = -2.0f * trKtK;
        const float detK = det3(Sxx, Sxy, Sxz, Syx, Syy, Syz, Szx, Szy, Szz);
        const float c1 = -8.0f * detK;
        const float c0 =
              N00 * det3(N11, N12, N13, N12, N22, N23, N13, N23, N33)
            - N01 * det3(N01, N12, N13, N02, N22, N23, N03, N23, N33)
            + N02 * det3(N01, N11, N13, N02, N12, N23, N03, N13, N33)
            - N03 * det3(N01, N11, N12, N02, N12, N22, N03, N13, N23);

        // Newton from guaranteed upper bound sqrt(3*trKtK) >= s1+s2+s3 >= lam_max
        float lam = sqrtf(fmaxf(3.0f * trKtK, 0.0f));
        #pragma unroll
        for (int it = 0; it < 14; ++it) {
            const float l2 = lam * lam;
            const float P  = (l2 + c2) * l2 + c1 * lam + c0;
            const float Pp = (4.0f * l2 + 2.0f * c2) * lam + c1;
            lam -= P / Pp;
        }

        // eigenvector of (N - lam I) via adjugate rows 0 and 1 (pick larger)
        const float M00 = N00 - lam, M11 = N11 - lam, M22 = N22 - lam, M33 = N33 - lam;
        const float a0 =  det3(M11, N12, N13, N12, M22, N23, N13, N23, M33);
        const float a1 = -det3(N01, N12, N13, N02, M22, N23, N03, N23, M33);
        const float a2 =  det3(N01, M11, N13, N02, N12, N23, N03, N13, M33);
        const float a3 = -det3(N01, M11, N12, N02, N12, M22, N03, N13, N23);
        const float b0 = -det3(N01, N02, N03, N12, M22, N23, N13, N23, M33);
        const float b1 =  det3(M00, N02, N03, N02, M22, N23, N03, N23, M33);
        const float b2 = -det3(M00, N01, N03, N02, N12, N23, N03, N13, M33);
        const float b3 =  det3(M00, N01, N02, N02, N12, M22, N03, N13, N23);
        const float na = a0 * a0 + a1 * a1 + a2 * a2 + a3 * a3;
        const float nb = b0 * b0 + b1 * b1 + b2 * b2 + b3 * b3;
        float qw, qx, qy, qz;
        if (na >= nb) { qw = a0; qx = a1; qy = a2; qz = a3; }
        else          { qw = b0; qx = b1; qy = b2; qz = b3; }
        const float qn = rsqrtf(fmaxf(qw * qw + qx * qx + qy * qy + qz * qz, 1e-30f));
        qw *= qn; qx *= qn; qy *= qn; qz *= qn;

        const float R00 = 1.0f - 2.0f * (qy * qy + qz * qz);
        const float R01 = 2.0f * (qx * qy - qw * qz);
        const float R02 = 2.0f * (qx * qz + qw * qy);
        const float R10 = 2.0f * (qx * qy + qw * qz);
        const float R11 = 1.0f - 2.0f * (qx * qx + qz * qz);
        const float R12 = 2.0f * (qy * qz - qw * qx);
        const float R20 = 2.0f * (qx * qz - qw * qy);
        const float R21 = 2.0f * (qy * qz + qw * qx);
        const float R22 = 1.0f - 2.0f * (qx * qx + qy * qy);

        const float trRK = R00 * Sxx + R01 * Syx + R02 * Szx
                         + R10 * Sxy + R11 * Syy + R12 * Szy
                         + R20 * Sxz + R21 * Syz + R22 * Szz;
        const float scale = trRK / var1;

        const float tx = mu2x - scale * (R00 * mu1x + R01 * mu1y + R02 * mu1z);
        const float ty = mu2y - scale * (R10 * mu1x + R11 * mu1y + R12 * mu1z);
        const float tz = mu2z - scale * (R20 * mu1x + R21 * mu1y + R22 * mu1z);

        // store scale-folded rotation + translation
        prm[lane][0] = scale * R00; prm[lane][1] = scale * R01; prm[lane][2] = scale * R02;
        prm[lane][3] = scale * R10; prm[lane][4] = scale * R11; prm[lane][5] = scale * R12;
        prm[lane][6] = scale * R20; prm[lane][7] = scale * R21; prm[lane][8] = scale * R22;
        prm[lane][9] = tx; prm[lane][10] = ty; prm[lane][11] = tz;
    }
    __syncthreads();

    // ---- phase 3: residual norms from register-held points ----
    float rsum = 0.0f;
    if (valid) {
        const float4* p4 = (const float4*)(&prm[wid][0]);
        const float4 pa = p4[0], pb = p4[1], pc = p4[2];
        const float sR00 = pa.x, sR01 = pa.y, sR02 = pa.z, sR10 = pa.w;
        const float sR11 = pb.x, sR12 = pb.y, sR20 = pb.z, sR21 = pb.w;
        const float sR22 = pc.x, tx = pc.y, ty = pc.z, tz = pc.w;

        #pragma unroll
        for (int j = 0; j < 3; ++j) {
            const int k = lane + 64 * j;
            if (k < KPTS) {
                const float ax = sR00 * tp[j][0] + sR01 * tp[j][1] + sR02 * tp[j][2] + tx;
                const float ay = sR10 * tp[j][0] + sR11 * tp[j][1] + sR12 * tp[j][2] + ty;
                const float az = sR20 * tp[j][0] + sR21 * tp[j][1] + sR22 * tp[j][2] + tz;
                const float dx = op[j][0] - ax;
                const float dy = op[j][1] - ay;
                const float dz = op[j][2] - az;
                rsum += sqrtf(dx * dx + dy * dy + dz * dz);
            }
        }
    }
    #pragma unroll
    for (int off = 32; off >= 1; off >>= 1)
        rsum += __shfl_xor(rsum, off, 64);

    if (lane == 0) shs[wid] = rsum;
    __syncthreads();
    if (threadIdx.x == 0) {
        float b = 0.0f;
        #pragma unroll
        for (int i = 0; i < WPB; ++i) b += shs[i];
        block_sums[blockIdx.x] = b;
    }
}

// Deterministic final reduction: one block, fixed summation order.
__global__ __launch_bounds__(256) void pa_reduce_kernel(
    const float* __restrict__ block_sums, int n,
    float* __restrict__ out, float inv_total)
{
    __shared__ float sh[4];
    float v = 0.0f;
    for (int i = threadIdx.x; i < n; i += 256) v += block_sums[i];
    #pragma unroll
    for (int off = 32; off >= 1; off >>= 1) v += __shfl_xor(v, off, 64);
    const int lane = threadIdx.x & 63;
    const int wid  = threadIdx.x >> 6;
    if (lane == 0) sh[wid] = v;
    __syncthreads();
    if (threadIdx.x == 0) out[0] = (sh[0] + sh[1] + sh[2] + sh[3]) * inv_total;
}

extern "C" void kernel_launch(void* const* d_in, const int* in_sizes, int n_in,
                              void* d_out, int out_size, void* d_ws, size_t ws_size,
                              hipStream_t stream) {
    const float* outp = (const float*)d_in[0];   // "output"
    const float* tgtp = (const float*)d_in[1];   // "target"
    const int nsamp   = in_sizes[0] / (KPTS * 3);
    const int nblocks = (nsamp + WPB - 1) / WPB;

    float* bsums = (float*)d_ws;

    pa_mpjpe_kernel<<<nblocks, 512, 0, stream>>>(outp, tgtp, bsums, nsamp);
    pa_reduce_kernel<<<1, 256, 0, stream>>>(
        bsums, nblocks, (float*)d_out,
        1.0f / ((float)nsamp * (float)KPTS));
}